// Round 18
// baseline (84.660 us; speedup 1.0000x reference)
//
#include <hip/hip_runtime.h>
#include <hip/hip_bf16.h>
#include <stdint.h>

#define N_NODES 100000
#define C 128
#define NET 7
#define E_EDGES 700000
#define S_SLOTS (N_NODES * NET)
#define BM 64
#define NB_CVTW 56              // 7*8*4*64/256
#define NB_SCAN ((E_EDGES + 255) / 256)

typedef __attribute__((ext_vector_type(8))) short short8;
typedef __attribute__((ext_vector_type(4))) float f32x4;
typedef __attribute__((ext_vector_type(4))) unsigned int uint4v;

// ---------- threefry2x32 (JAX), verified round 2 ----------
struct TF2 { uint32_t a, b; };

__host__ __device__ constexpr uint32_t rotl32c(uint32_t v, int r) {
    return (v << r) | (v >> (32 - r));
}

__host__ __device__ constexpr TF2 threefry2x32(uint32_t k0, uint32_t k1,
                                               uint32_t x0, uint32_t x1) {
    const uint32_t ks0 = k0, ks1 = k1, ks2 = 0x1BD11BDAu ^ k0 ^ k1;
    x0 += ks0; x1 += ks1;
#define RND(r) { x0 += x1; x1 = rotl32c(x1, (r)); x1 ^= x0; }
    RND(13) RND(15) RND(26) RND(6)
    x0 += ks1; x1 += ks2 + 1u;
    RND(17) RND(29) RND(16) RND(24)
    x0 += ks2; x1 += ks0 + 2u;
    RND(13) RND(15) RND(26) RND(6)
    x0 += ks0; x1 += ks1 + 3u;
    RND(17) RND(29) RND(16) RND(24)
    x0 += ks1; x1 += ks2 + 4u;
    RND(13) RND(15) RND(26) RND(6)
    x0 += ks2; x1 += ks0 + 5u;
#undef RND
    return TF2{x0, x1};
}

constexpr TF2 K2 = threefry2x32(0u, 42u, 0u, 1u);  // split(key(42),2)[1]

__device__ __forceinline__ uint32_t jax_bits32(uint32_t f) {
    TF2 o = threefry2x32(K2.a, K2.b, 0u, f);
    return o.a ^ o.b;
}

__device__ __forceinline__ unsigned short f2bf(float f) {
    uint32_t u = __float_as_uint(f);
    u += 0x7fffu + ((u >> 16) & 1u);
    return (unsigned short)(u >> 16);
}

// truncation pack: two fp32 -> one dword of two bf16 (lo, hi)  [verified r14/r16]
__device__ __forceinline__ uint32_t pk(float lo, float hi) {
    return (__float_as_uint(hi) & 0xffff0000u) | (__float_as_uint(lo) >> 16);
}

// pack 8 fp32 -> uint4v of 8 bf16 (no scaling)
__device__ __forceinline__ uint4v packraw(f32x4 a, f32x4 b) {
    uint4v o;
    o.x = pk(a.x, a.y); o.y = pk(a.z, a.w);
    o.z = pk(b.x, b.y); o.w = pk(b.z, b.w);
    return o;
}

// sum two packed-bf16 dwords -> packed bf16 (truncation; x0.5 folded into Wf) [r5-r12]
__device__ __forceinline__ uint32_t sumpack(uint32_t a, uint32_t b) {
    float alo = __uint_as_float(a << 16);
    float ahi = __uint_as_float(a & 0xffff0000u);
    float blo = __uint_as_float(b << 16);
    float bhi = __uint_as_float(b & 0xffff0000u);
    return (__float_as_uint(ahi + bhi) & 0xffff0000u) | (__float_as_uint(alo + blo) >> 16);
}

__device__ __forceinline__ uint4v sumpack4(uint4v a, uint4v b) {
    uint4v o;
    o.x = sumpack(a.x, b.x); o.y = sumpack(a.y, b.y);
    o.z = sumpack(a.z, b.z); o.w = sumpack(a.w, b.w);
    return o;
}

// ---------- prep: cvt_w (frag-major, x0.5) || edge run-scan sampling  [r16] ----------
// pairs (pre-zeroed): (0,0)=empty; (n+1,0)=single source n; (n0+1,n1+1)=two sources.
__global__ __launch_bounds__(256) void prep(const float* __restrict__ W,
                                            const int* __restrict__ idx,
                                            const int* __restrict__ col,
                                            unsigned short* __restrict__ Wf,
                                            int2* __restrict__ pairs) {
    const int b = blockIdx.x;
    if (b < NB_CVTW) {
        // Wf[((et*8+n16)*4+ks)*512 + lane*8 + j] = 0.5 * W  (frag-major, verified round 4)
        int t = b * 256 + threadIdx.x;   // < 14336
        int l = t & 63, ks = (t >> 6) & 3, n16 = (t >> 8) & 7, et = t >> 11;
        int n = n16 * 16 + (l & 15);
        int k0 = ks * 32 + (l >> 4) * 8;
        union { unsigned short u[8]; uint4v q; } o;
#pragma unroll
        for (int j = 0; j < 8; j++)
            o.u[j] = f2bf(0.5f * W[(size_t)(et * 128 + k0 + j) * 128 + n]);
        ((uint4v*)Wf)[t] = o.q;
    } else {
        int e = (b - NB_CVTW) * 256 + threadIdx.x;
        if (e >= E_EDGES) return;
        int s = idx[e];
        if (e > 0 && idx[e - 1] == s) return;       // not a run start
        if (s % NET == NET - 1) return;             // self slot: synthesized in fused
        int len = 1;
        while (e + len < E_EDGES && idx[e + len] == s) ++len;
        uint32_t b0 = jax_bits32((uint32_t)s * 2u + 0u) & 0x3FFFFFFFu;
        uint32_t b1 = jax_bits32((uint32_t)s * 2u + 1u) & 0x3FFFFFFFu;
        int c0 = col[e + (int)(b0 % (uint32_t)len)];
        int c1 = col[e + (int)(b1 % (uint32_t)len)];
        pairs[s] = (c0 == c1) ? make_int2(c0 + 1, 0)
                              : make_int2(c0 + 1, c1 + 1);
    }
}

// ---------- fused: fp32 gather -> bf16-resident 2-set lookahead + bf16 MFMA ----------
// BM=64 x 128 tile, 512 thr = 8 waves; wave w: 64 rows x cols w*16..+15 (fm=4, fn=1).
// GLOAD loads fp32 x rows and IMMEDIATELY truncate-packs each source to bf16 — the
// persistent lookahead state is bf16-sized (same footprint as r12, which didn't spill;
// r14's fp32-resident sets did). 2 sets, consumed 1 iter after issue (gap = MFMA +
// barrier + B + G >= ~1500 cy > 900 cy worst-case gather latency). B reg-dbuf issued
// FIRST (oldest in FIFO). Barrier = lgkmcnt(0)+s_barrier. LDS chunk^(row&7) both sides.
__global__ __launch_bounds__(512, 4) void fused_mfma(const float* __restrict__ x,
                                                     const int2* __restrict__ pairs,
                                                     const unsigned short* __restrict__ Wf,
                                                     float* __restrict__ out) {
    __shared__ unsigned char Alds[2][BM * 256];     // 32 KiB
    const int tid  = threadIdx.x;
    const int nb   = blockIdx.x * BM;
    const int wave = tid >> 6, lane = tid & 63;
    const int lr   = lane & 15, lg = lane >> 4;
    const char* xfc = (const char*)x;

    // staging: thread t owns row t>>3, bf16 chunks q and q+8 (q = t&7)
    const int srow = tid >> 3;
    const int q32  = (tid & 7) * 32;                // fp32 byte offset of chunk q
    const int arow = nb + srow;
    const int prow = (arow < N_NODES) ? arow * NET : -1;
    const int sa0  = srow * 256 + ((tid & 7) ^ (srow & 7)) * 16;
    const int sa1  = sa0 + 128;

    uint4v g0[2][2], g1[2][2];   // 2 lookahead sets, bf16-packed (4 VGPR per chunk)
    int2   pset[2];
    short8 bfr[2][4];            // B double buffer

// load fp32, pack per-source to bf16, keep only bf16 (transient fp32 freed)
#define GLOAD(SET, PV) { \
    int2 p_ = (PV); pset[SET] = p_; \
    if (p_.x > 0) { \
        const char* b0_ = xfc + ((size_t)(p_.x - 1) << 9) + q32; \
        g0[SET][0] = packraw(*(const f32x4*)(b0_),       *(const f32x4*)(b0_ + 16)); \
        g0[SET][1] = packraw(*(const f32x4*)(b0_ + 256), *(const f32x4*)(b0_ + 272)); \
        if (p_.y > 0) { \
            const char* b1_ = xfc + ((size_t)(p_.y - 1) << 9) + q32; \
            g1[SET][0] = packraw(*(const f32x4*)(b1_),       *(const f32x4*)(b1_ + 16)); \
            g1[SET][1] = packraw(*(const f32x4*)(b1_ + 256), *(const f32x4*)(b1_ + 272)); \
        } \
    } }

#define COMBINE(SET, BUF) { \
    int2 p_ = pset[SET]; \
    uint4v v0_, v1_; \
    if (p_.x <= 0) { \
        uint4v z_ = {0u, 0u, 0u, 0u}; v0_ = z_; v1_ = z_; \
    } else if (p_.y <= 0) { \
        v0_ = g0[SET][0] + 0x00800080u;   /* exact x2: exponent+1 per bf16 half */ \
        v1_ = g0[SET][1] + 0x00800080u; \
    } else { \
        v0_ = sumpack4(g0[SET][0], g1[SET][0]); \
        v1_ = sumpack4(g0[SET][1], g1[SET][1]); \
    } \
    *(uint4v*)(&Alds[BUF][sa0]) = v0_; \
    *(uint4v*)(&Alds[BUF][sa1]) = v1_; }

// B slice for this wave (cols wave*16..+15), frag-major Wf (verified)
#define LOADB(DST, ET) { _Pragma("unroll") \
    for (int ks_ = 0; ks_ < 4; ks_++) \
        (DST)[ks_] = *(const short8*)(Wf \
            + (size_t)((((ET) * 8 + wave) * 4 + ks_) * 512) + lane * 8); }

#define BARRIER() { \
    asm volatile("s_waitcnt lgkmcnt(0)" ::: "memory"); \
    __builtin_amdgcn_s_barrier(); \
    __builtin_amdgcn_sched_barrier(0); }

    f32x4 acc[4];
#pragma unroll
    for (int i = 0; i < 4; i++) acc[i] = (f32x4)0.f;

    // pairs for et 0..5 (self slot et6 synthesized as single-source)
    int2 pj[7];
#pragma unroll
    for (int j = 0; j < 6; j++)
        pj[j] = (prow >= 0) ? pairs[prow + j] : make_int2(0, 0);
    pj[6] = (prow >= 0) ? make_int2(arow + 1, 0) : make_int2(0, 0);

    // prologue: set0 <- et0, set1 <- et1; B(0); combine et0 -> buf0
    GLOAD(0, pj[0])
    GLOAD(1, pj[1])
    LOADB(bfr[0], 0)
    COMBINE(0, 0)
    BARRIER()

#pragma unroll
    for (int et = 0; et < NET; ++et) {
        const int cur = et & 1;

        // 1) B for et+1 FIRST (oldest VMEM entry -> its wait never drains gathers)
        if (et + 1 < NET) LOADB(bfr[cur ^ 1], et + 1)

        // 2) gathers for et+2 into the set freed last iteration (set[et&1])
        if (et + 2 < NET) GLOAD(cur, pj[et + 2])

        // 3) combine et+1 (set issued 1 iter ago; ~1500cy in flight) -> buf[cur^1]
        if (et + 1 < NET) COMBINE(cur ^ 1, cur ^ 1)

        // 4) MFMA(et): 4 ks x { 4 ds_read_b128 (swizzled), 4 mfma }, B from regs
        __builtin_amdgcn_s_setprio(1);
#pragma unroll
        for (int ks = 0; ks < 4; ks++) {
            const int coff = (((ks * 4 + lg) ^ (lr & 7)) << 4);
            short8 b_ = bfr[cur][ks];
#pragma unroll
            for (int fm = 0; fm < 4; fm++) {
                short8 a_ = *(const short8*)(&Alds[cur][(fm * 16 + lr) * 256 + coff]);
                acc[fm] = __builtin_amdgcn_mfma_f32_16x16x32_bf16(a_, b_, acc[fm], 0, 0, 0);
            }
        }
        __builtin_amdgcn_s_setprio(0);

        // 5) lgkm-only barrier (gathers stay in flight)
        if (et + 1 < NET) BARRIER()
    }

    // epilogue: D layout col=lane&15, row=(lane>>4)*4+reg (verified)
#pragma unroll
    for (int fm = 0; fm < 4; fm++) {
        int row0 = nb + fm * 16 + lg * 4;
        int colo = wave * 16 + lr;
#pragma unroll
        for (int j = 0; j < 4; j++)
            if (row0 + j < N_NODES)
                out[(size_t)(row0 + j) * C + colo] = acc[fm][j];
    }
#undef GLOAD
#undef COMBINE
#undef LOADB
#undef BARRIER
}

extern "C" void kernel_launch(void* const* d_in, const int* in_sizes, int n_in,
                              void* d_out, int out_size, void* d_ws, size_t ws_size,
                              hipStream_t stream) {
    const float* x   = (const float*)d_in[0];
    const int*   col = (const int*)d_in[1];
    const int*   idx = (const int*)d_in[2];
    const float* W   = (const float*)d_in[3];
    float* out = (float*)d_out;

    int2* pairs        = (int2*)d_ws;                               // 5.6 MB
    unsigned short* Wf = (unsigned short*)((char*)pairs + (size_t)S_SLOTS * 8);  // 229 KB

    hipMemsetAsync(pairs, 0, (size_t)S_SLOTS * sizeof(int2), stream);  // empty = (0,0)
    prep<<<NB_CVTW + NB_SCAN, 256, 0, stream>>>(W, idx, col, Wf, pairs);
    fused_mfma<<<(N_NODES + BM - 1) / BM, 512, 0, stream>>>(x, pairs, Wf, out);
}